// Round 8
// baseline (97.987 us; speedup 1.0000x reference)
//
#include <hip/hip_runtime.h>
#include <hip/hip_bf16.h>

// DEC ClusteringLayer: q[i][j] = (1/(1+||x_i-c_j||^2)) / rowsum, ALPHA=1.
// Round 8: PERSISTENT PIPELINED kernel. 256 blocks (1/CU), each owns 4
// consecutive 64-row tiles. Double-buffered 64KB LDS A-tiles (fragment order,
// conflict-free contiguous ds_write/ds_read). Per tile: GEMM(i) overlaps the
// in-flight x-loads of tile i+1; cvt+ds_write after epilogue (max latency
// cover); barriers are lgkm-only so global prefetches survive. vmcnt ordering:
// all 16 B-image loads of tile i are issued BEFORE the x-clump of tile i+1
// (B refills for bodies 12-15 wrap to next tile's images 0-3 post-clump).
// B (clusters, bf16, L2-resident) pre-packed fragment-order, depth-4 reg sets.

typedef __attribute__((ext_vector_type(8))) short short8v;
typedef __attribute__((ext_vector_type(4))) float f32x4;

#define DDIM 512
#define KCL  256
#define BM   64
#define NT   512
#define BTILE 8192       // shorts per fragment-order B image (256 x 32)
#define TPB  4           // tiles per block

__device__ __forceinline__ short f2bf(float f) {
    __hip_bfloat16 h = __float2bfloat16(f);
    return __builtin_bit_cast(short, h);
}

// ---- pre-kernel: blocks 0..63 pack clusters -> bf16 fragment-order images;
//      blocks 64..79 compute ||c||^2 ----
__global__ void prep(const float* __restrict__ cl, short* __restrict__ wsB,
                     float* __restrict__ wsC2) {
    const int t = threadIdx.x;
    if (blockIdx.x < 64) {
        const int u = blockIdx.x * 256 + t;
        const int img = u >> 10, gi = u & 1023;
        const int g = gi >> 6, lq = (gi >> 4) & 3, l15 = gi & 15;
        const float* src = cl + (size_t)(g * 16 + l15) * DDIM + img * 32 + lq * 8;
        float4 a = *(const float4*)src;
        float4 b = *(const float4*)(src + 4);
        short8v s;
        s[0]=f2bf(a.x); s[1]=f2bf(a.y); s[2]=f2bf(a.z); s[3]=f2bf(a.w);
        s[4]=f2bf(b.x); s[5]=f2bf(b.y); s[6]=f2bf(b.z); s[7]=f2bf(b.w);
        *(short8v*)&wsB[(size_t)u * 8] = s;
    } else {
        const int cidx = (blockIdx.x - 64) * 16 + (t >> 4);
        const int j = t & 15;
        const float* src = cl + (size_t)cidx * DDIM + j * 32;
        float s = 0.f;
#pragma unroll
        for (int i = 0; i < 8; ++i) {
            float4 v = ((const float4*)src)[i];
            s += v.x*v.x + v.y*v.y + v.z*v.z + v.w*v.w;
        }
        s += __shfl_xor(s, 1); s += __shfl_xor(s, 2);
        s += __shfl_xor(s, 4); s += __shfl_xor(s, 8);
        if (j == 0) wsC2[cidx] = s;
    }
}

#define BAR()    asm volatile("s_waitcnt lgkmcnt(0)\ns_barrier" ::: "memory")
#define SFENCE() __builtin_amdgcn_sched_barrier(0)

__global__ __launch_bounds__(NT, 2)
void dec_main(const float* __restrict__ x, const short* __restrict__ wsB,
              const float* __restrict__ wsC2, float* __restrict__ out) {
    __shared__ __align__(16) short lA[2][32768];   // 2 x 64 KB fragment-order A tiles
    __shared__ float s_x2p[2][2][BM];              // [parity][col-half][row]
    __shared__ float s_rs[4][BM];

    const int t = threadIdx.x, lane = t & 63, w = t >> 6;
    const int rg = w >> 2, cg = w & 3;
    const int l15 = lane & 15, lq = lane >> 4;
    const int row0 = blockIdx.x * (TPB * BM);

    // staging: thread covers row (w&3)*16+l15, cols (w>>2)*32+lq*8 (+CP*64)
    const int srowS = (w & 3) * 16 + l15;
    const int scolS = (w >> 2) * 32 + lq * 8;
    const float* xs = x + (size_t)(row0 + srowS) * DDIM + scolS;
    const short* bb = wsB + (size_t)(cg * 4) * 512 + (size_t)lane * 8;

    float c2a[4];
#pragma unroll
    for (int n = 0; n < 4; ++n) c2a[n] = wsC2[cg*64 + n*16 + l15];

    f32x4 acc[2][4];
    float x2p;
    short8v Ba[4], Bb[4], Bc[4], Bd[4];
    float4 G0a,G0b,G1a,G1b,G2a,G2b,G3a,G3b,G4a,G4b,G5a,G5b,G6a,G6b,G7a,G7b;

#define LOADB(TT, S)                                         \
    {  const short* bt = bb + (size_t)(TT) * BTILE;          \
       S[0] = *(const short8v*)(bt);                         \
       S[1] = *(const short8v*)(bt + 512);                   \
       S[2] = *(const short8v*)(bt + 1024);                  \
       S[3] = *(const short8v*)(bt + 1536); }

#define GISSUE(IT)                                                   \
    {  const float* xg = xs + (size_t)(IT) * (BM * DDIM);            \
       G0a = *(const float4*)(xg);       G0b = *(const float4*)(xg + 4);   \
       G1a = *(const float4*)(xg + 64);  G1b = *(const float4*)(xg + 68);  \
       G2a = *(const float4*)(xg + 128); G2b = *(const float4*)(xg + 132); \
       G3a = *(const float4*)(xg + 192); G3b = *(const float4*)(xg + 196); \
       G4a = *(const float4*)(xg + 256); G4b = *(const float4*)(xg + 260); \
       G5a = *(const float4*)(xg + 320); G5b = *(const float4*)(xg + 324); \
       G6a = *(const float4*)(xg + 384); G6b = *(const float4*)(xg + 388); \
       G7a = *(const float4*)(xg + 448); G7b = *(const float4*)(xg + 452); }

#define STG1(PARN, CP, GA, GB)                                                   \
    {  short8v s_;                                                               \
       s_[0]=f2bf(GA.x); s_[1]=f2bf(GA.y); s_[2]=f2bf(GA.z); s_[3]=f2bf(GA.w);   \
       s_[4]=f2bf(GB.x); s_[5]=f2bf(GB.y); s_[6]=f2bf(GB.z); s_[7]=f2bf(GB.w);   \
       x2p += GA.x*GA.x + GA.y*GA.y + GA.z*GA.z + GA.w*GA.w                      \
            + GB.x*GB.x + GB.y*GB.y + GB.z*GB.z + GB.w*GB.w;                     \
       *(short8v*)&lA[PARN][(CP)*4096 + t*8] = s_; }

#define CVT(PARN)                                                                \
    {  x2p = 0.f;                                                                \
       STG1(PARN,0,G0a,G0b) STG1(PARN,1,G1a,G1b)                                 \
       STG1(PARN,2,G2a,G2b) STG1(PARN,3,G3a,G3b)                                 \
       STG1(PARN,4,G4a,G4b) STG1(PARN,5,G5a,G5b)                                 \
       STG1(PARN,6,G6a,G6b) STG1(PARN,7,G7a,G7b)                                 \
       x2p += __shfl_xor(x2p,16); x2p += __shfl_xor(x2p,32);                     \
       if (lane < 16) s_x2p[PARN][w>>2][(w&3)*16 + lane] = x2p; }

#define BODY(KK, PAR, SU, RF)                                                    \
    {  const short* aB_ = &lA[PAR][rg*1024 + lane*8 + (KK)*2048];                \
       short8v a0_ = *(const short8v*)aB_;                                       \
       short8v a1_ = *(const short8v*)(aB_ + 512);                               \
       acc[0][0] = __builtin_amdgcn_mfma_f32_16x16x32_bf16(a0_, SU[0], acc[0][0], 0,0,0); \
       acc[0][1] = __builtin_amdgcn_mfma_f32_16x16x32_bf16(a0_, SU[1], acc[0][1], 0,0,0); \
       acc[0][2] = __builtin_amdgcn_mfma_f32_16x16x32_bf16(a0_, SU[2], acc[0][2], 0,0,0); \
       acc[0][3] = __builtin_amdgcn_mfma_f32_16x16x32_bf16(a0_, SU[3], acc[0][3], 0,0,0); \
       acc[1][0] = __builtin_amdgcn_mfma_f32_16x16x32_bf16(a1_, SU[0], acc[1][0], 0,0,0); \
       acc[1][1] = __builtin_amdgcn_mfma_f32_16x16x32_bf16(a1_, SU[1], acc[1][1], 0,0,0); \
       acc[1][2] = __builtin_amdgcn_mfma_f32_16x16x32_bf16(a1_, SU[2], acc[1][2], 0,0,0); \
       acc[1][3] = __builtin_amdgcn_mfma_f32_16x16x32_bf16(a1_, SU[3], acc[1][3], 0,0,0); \
       if (RF) { LOADB(((KK)+4)&15, SU); } }

#define ITER(IT, PAR, PARN)                                                      \
    {  _Pragma("unroll") for (int m=0;m<2;++m)                                   \
       _Pragma("unroll") for (int n=0;n<4;++n) acc[m][n]=(f32x4){0.f,0.f,0.f,0.f}; \
       BODY(0,PAR,Ba,1)  BODY(1,PAR,Bb,1)  BODY(2,PAR,Bc,1)  BODY(3,PAR,Bd,1)    \
       BODY(4,PAR,Ba,1)  BODY(5,PAR,Bb,1)  BODY(6,PAR,Bc,1)  BODY(7,PAR,Bd,1)    \
       BODY(8,PAR,Ba,1)  BODY(9,PAR,Bb,1)  BODY(10,PAR,Bc,1) BODY(11,PAR,Bd,1)   \
       SFENCE();                                                                 \
       if ((IT) < TPB-1) { GISSUE((IT)+1); }                                     \
       SFENCE();                                                                 \
       BODY(12,PAR,Ba,(IT)<TPB-1) BODY(13,PAR,Bb,(IT)<TPB-1)                     \
       BODY(14,PAR,Bc,(IT)<TPB-1) BODY(15,PAR,Bd,(IT)<TPB-1)                     \
       /* epilogue: d2 -> q_unnorm (C/D: col=l15, row=lq*4+r) */                 \
       _Pragma("unroll") for (int m=0;m<2;++m)                                   \
       _Pragma("unroll") for (int n=0;n<4;++n)                                   \
       _Pragma("unroll") for (int r=0;r<4;++r) {                                 \
           const int rw = rg*32 + m*16 + lq*4 + r;                               \
           const float x2v = s_x2p[PAR][0][rw] + s_x2p[PAR][1][rw];              \
           float d2 = fmaxf(x2v + c2a[n] - 2.0f*acc[m][n][r], 0.0f);             \
           acc[m][n][r] = 1.0f/(1.0f + d2); }                                    \
       _Pragma("unroll") for (int m=0;m<2;++m)                                   \
       _Pragma("unroll") for (int r=0;r<4;++r) {                                 \
           float p = acc[m][0][r]+acc[m][1][r]+acc[m][2][r]+acc[m][3][r];        \
           p += __shfl_xor(p,1); p += __shfl_xor(p,2);                           \
           p += __shfl_xor(p,4); p += __shfl_xor(p,8);                           \
           if (l15 == 0) s_rs[cg][rg*32 + m*16 + lq*4 + r] = p; }                \
       BAR();                                                                    \
       _Pragma("unroll") for (int m=0;m<2;++m)                                   \
       _Pragma("unroll") for (int r=0;r<4;++r) {                                 \
           const int rw = rg*32 + m*16 + lq*4 + r;                               \
           const float rinv = 1.0f/(s_rs[0][rw]+s_rs[1][rw]+s_rs[2][rw]+s_rs[3][rw]); \
           float* o = out + (size_t)(row0 + (IT)*BM + rw)*KCL + cg*64 + l15;     \
           _Pragma("unroll") for (int n=0;n<4;++n) o[n*16] = acc[m][n][r]*rinv; }\
       if ((IT) < TPB-1) { CVT(PARN); }                                          \
       BAR(); }

    // ---- prologue: B(0..3) issued FIRST (vmcnt order), then x-clump(0), cvt ----
    LOADB(0, Ba); LOADB(1, Bb); LOADB(2, Bc); LOADB(3, Bd);
    SFENCE();
    GISSUE(0);
    SFENCE();
    CVT(0);
    BAR();

    ITER(0, 0, 1)
    ITER(1, 1, 0)
    ITER(2, 0, 1)
    ITER(3, 1, 0)
}

extern "C" void kernel_launch(void* const* d_in, const int* in_sizes, int n_in,
                              void* d_out, int out_size, void* d_ws, size_t ws_size,
                              hipStream_t stream) {
    const float* x  = (const float*)d_in[0];
    const float* cl = (const float*)d_in[1];
    float* out = (float*)d_out;
    short* wsB  = (short*)d_ws;
    float* wsC2 = (float*)((char*)d_ws + (size_t)16 * BTILE * sizeof(short)); // +256 KB

    prep<<<80, 256, 0, stream>>>(cl, wsB, wsC2);
    const int B = in_sizes[0] / DDIM;     // 65536
    dec_main<<<B / (BM * TPB), NT, 0, stream>>>(x, wsB, wsC2, out);
}

// Round 9
// 54.069 us; speedup vs baseline: 1.8122x; 1.8122x over previous
//
#include <hip/hip_runtime.h>
#include <hip/hip_bf16.h>

// DEC ClusteringLayer: q[i][j] = (1/(1+||x_i-c_j||^2)) / rowsum, ALPHA=1.
// Round 9 = Round 2 (measured best, 55.7us) + counted-vmcnt barriers (T4):
// B staged per-tile into LDS via global_load_lds (16KB image, issued one full
// tile ahead); A staged via 1 float4/thread -> cvt -> 8B ds_write, X prefetch
// depth-3 (named X0/X1/X2, full 16x literal unroll); every barrier is
// `s_waitcnt vmcnt(N) lgkmcnt(0); s_barrier` with N counted so the B-DMA and
// X loads survive the barrier. No reg-staging clumps (3 spills taught us).

typedef __attribute__((ext_vector_type(4))) short short4v;
typedef __attribute__((ext_vector_type(8))) short short8v;
typedef __attribute__((ext_vector_type(4))) float f32x4;

#define DDIM 512
#define KCL  256
#define BM   64
#define NT   512
#define NTILES 16
#define BTILE  8192      // shorts per fragment-order B image (256 x 32)

__device__ __forceinline__ short f2bf(float f) {
    __hip_bfloat16 h = __float2bfloat16(f);
    return __builtin_bit_cast(short, h);
}

__device__ __forceinline__ void glds16(const void* g, void* l) {
    __builtin_amdgcn_global_load_lds(
        (const __attribute__((address_space(1))) unsigned int*)g,
        (__attribute__((address_space(3))) unsigned int*)l, 16, 0, 0);
}

// ---- pre-kernel: blocks 0..63 pack clusters -> bf16 fragment-order images;
//      blocks 64..79 compute ||c||^2 ----
__global__ void prep(const float* __restrict__ cl, short* __restrict__ wsB,
                     float* __restrict__ wsC2) {
    const int t = threadIdx.x;
    if (blockIdx.x < 64) {
        const int u = blockIdx.x * 256 + t;
        const int img = u >> 10, gi = u & 1023;
        const int g = gi >> 6, lq = (gi >> 4) & 3, l15 = gi & 15;
        const float* src = cl + (size_t)(g * 16 + l15) * DDIM + img * 32 + lq * 8;
        float4 a = *(const float4*)src;
        float4 b = *(const float4*)(src + 4);
        short8v s;
        s[0]=f2bf(a.x); s[1]=f2bf(a.y); s[2]=f2bf(a.z); s[3]=f2bf(a.w);
        s[4]=f2bf(b.x); s[5]=f2bf(b.y); s[6]=f2bf(b.z); s[7]=f2bf(b.w);
        *(short8v*)&wsB[(size_t)u * 8] = s;
    } else {
        const int cidx = (blockIdx.x - 64) * 16 + (t >> 4);
        const int j = t & 15;
        const float* src = cl + (size_t)cidx * DDIM + j * 32;
        float s = 0.f;
#pragma unroll
        for (int i = 0; i < 8; ++i) {
            float4 v = ((const float4*)src)[i];
            s += v.x*v.x + v.y*v.y + v.z*v.z + v.w*v.w;
        }
        s += __shfl_xor(s, 1); s += __shfl_xor(s, 2);
        s += __shfl_xor(s, 4); s += __shfl_xor(s, 8);
        if (j == 0) wsC2[cidx] = s;
    }
}

#define SFENCE() __builtin_amdgcn_sched_barrier(0)
#define BARV1() asm volatile("s_waitcnt vmcnt(1) lgkmcnt(0)\ns_barrier" ::: "memory")
#define BARV0() asm volatile("s_waitcnt vmcnt(0) lgkmcnt(0)\ns_barrier" ::: "memory")
#define BARV2() asm volatile("s_waitcnt vmcnt(2) lgkmcnt(0)\ns_barrier" ::: "memory")

__global__ __launch_bounds__(NT, 4)
void dec_main(const float* __restrict__ x, const short* __restrict__ wsB,
              const float* __restrict__ wsC2, float* __restrict__ out) {
    __shared__ __align__(16) short lA[2][2048];   // 2 x 4 KB fragment-order A tiles
    __shared__ __align__(16) short lB[2][8192];   // 2 x 16 KB fragment-order B tiles
    __shared__ float s_x2[BM];
    __shared__ float s_rs[4][BM];

    const int t = threadIdx.x, lane = t & 63, w = t >> 6;
    const int rg = w >> 2, cg = w & 3;
    const int l15 = lane & 15, lq = lane >> 4;
    const int row0 = blockIdx.x * BM;

    // A staging: thread t covers row srow = t>>3, floats sk4 = (t&7)*4 per tile
    const int srow = t >> 3;
    const int sk4  = (t & 7) << 2;
    const float* xs = x + (size_t)(row0 + srow) * DDIM + sk4;
    // fragment-order A slot (shorts): [srow>>4][l15=srow&15][lq=sk4>>3][half]
    const int awr = (srow >> 4) * 512 + (srow & 15) * 32
                  + ((t & 7) >> 1) * 8 + ((t & 7) & 1) * 4;

    f32x4 acc[2][4];
#pragma unroll
    for (int m = 0; m < 2; ++m)
#pragma unroll
        for (int n = 0; n < 4; ++n) acc[m][n] = (f32x4){0.f,0.f,0.f,0.f};
    float x2p = 0.f;
    float4 X0, X1, X2;

#define GLDS(TT, LBN)                                        \
    {  const short* src_ = wsB + (size_t)(TT) * BTILE;       \
       glds16(src_ + t * 8,        (LBN) + t * 8);           \
       glds16(src_ + 4096 + t * 8, (LBN) + 4096 + t * 8); }

#define LOADX(TT, XR)  { XR = *(const float4*)(xs + (TT) * 32); }

#define CVT(XR, LAN)                                                             \
    {  short4v s_;                                                               \
       s_[0]=f2bf(XR.x); s_[1]=f2bf(XR.y); s_[2]=f2bf(XR.z); s_[3]=f2bf(XR.w);   \
       x2p += XR.x*XR.x + XR.y*XR.y + XR.z*XR.z + XR.w*XR.w;                     \
       *(short4v*)&(LAN)[awr] = s_; }

#define MSTEP(LAN, LBN)                                                          \
    {  short8v a0 = *(const short8v*)&(LAN)[rg*1024 + l15*32 + lq*8];            \
       short8v a1 = *(const short8v*)&(LAN)[rg*1024 + 512 + l15*32 + lq*8];      \
       short8v b0 = *(const short8v*)&(LBN)[cg*2048 + lane*8];                   \
       short8v b1 = *(const short8v*)&(LBN)[cg*2048 + 512  + lane*8];            \
       short8v b2 = *(const short8v*)&(LBN)[cg*2048 + 1024 + lane*8];            \
       short8v b3 = *(const short8v*)&(LBN)[cg*2048 + 1536 + lane*8];            \
       acc[0][0] = __builtin_amdgcn_mfma_f32_16x16x32_bf16(a0, b0, acc[0][0], 0,0,0); \
       acc[0][1] = __builtin_amdgcn_mfma_f32_16x16x32_bf16(a0, b1, acc[0][1], 0,0,0); \
       acc[0][2] = __builtin_amdgcn_mfma_f32_16x16x32_bf16(a0, b2, acc[0][2], 0,0,0); \
       acc[0][3] = __builtin_amdgcn_mfma_f32_16x16x32_bf16(a0, b3, acc[0][3], 0,0,0); \
       acc[1][0] = __builtin_amdgcn_mfma_f32_16x16x32_bf16(a1, b0, acc[1][0], 0,0,0); \
       acc[1][1] = __builtin_amdgcn_mfma_f32_16x16x32_bf16(a1, b1, acc[1][1], 0,0,0); \
       acc[1][2] = __builtin_amdgcn_mfma_f32_16x16x32_bf16(a1, b2, acc[1][2], 0,0,0); \
       acc[1][3] = __builtin_amdgcn_mfma_f32_16x16x32_bf16(a1, b3, acc[1][3], 0,0,0); }

    // ITER(J): tile J from (AC,BC); stage tile J+1 into (AN,BN) [B-DMA issued
    // FIRST so the end-of-iter wait is vmcnt(1)]; X(J+3) issued LAST.
#define ITER(J, AC, BC, AN, BN, XC, XL)                                          \
    {  if ((J) + 1 < NTILES) GLDS((J) + 1, BN);                                  \
       SFENCE();                                                                 \
       if ((J) + 1 < NTILES) CVT(XC, AN);                                        \
       MSTEP(AC, BC);                                                            \
       SFENCE();                                                                 \
       if ((J) + 3 < NTILES) { LOADX((J) + 3, XL); }                             \
       SFENCE();                                                                 \
       if ((J) + 1 < NTILES) { if ((J) + 3 < NTILES) BARV1(); else BARV0(); } }

    // ---- prologue: X(0) first, then B(0) DMA, then X(1),X(2) ----
    LOADX(0, X0);
    GLDS(0, lB[0]);
    LOADX(1, X1);
    LOADX(2, X2);
    SFENCE();
    CVT(X0, lA[0]);          // compiler-counted wait: only X0 drained
    SFENCE();
    BARV2();                 // B(0) DMA done; X1,X2 stay in flight

    ITER( 0, lA[0], lB[0], lA[1], lB[1], X1, X0)
    ITER( 1, lA[1], lB[1], lA[0], lB[0], X2, X1)
    ITER( 2, lA[0], lB[0], lA[1], lB[1], X0, X2)
    ITER( 3, lA[1], lB[1], lA[0], lB[0], X1, X0)
    ITER( 4, lA[0], lB[0], lA[1], lB[1], X2, X1)
    ITER( 5, lA[1], lB[1], lA[0], lB[0], X0, X2)
    ITER( 6, lA[0], lB[0], lA[1], lB[1], X1, X0)
    ITER( 7, lA[1], lB[1], lA[0], lB[0], X2, X1)
    ITER( 8, lA[0], lB[0], lA[1], lB[1], X0, X2)
    ITER( 9, lA[1], lB[1], lA[0], lB[0], X1, X0)
    ITER(10, lA[0], lB[0], lA[1], lB[1], X2, X1)
    ITER(11, lA[1], lB[1], lA[0], lB[0], X0, X2)
    ITER(12, lA[0], lB[0], lA[1], lB[1], X1, X0)
    ITER(13, lA[1], lB[1], lA[0], lB[0], X2, X1)
    ITER(14, lA[0], lB[0], lA[1], lB[1], X0, X0)
    ITER(15, lA[1], lB[1], lA[0], lB[0], X0, X0)

    // ---- ||x||^2: 8 staging threads per row (consecutive lanes) ----
    x2p += __shfl_xor(x2p, 1); x2p += __shfl_xor(x2p, 2); x2p += __shfl_xor(x2p, 4);
    if ((t & 7) == 0) s_x2[srow] = x2p;
    __syncthreads();

    // ---- epilogue: d2 -> q_unnorm (C/D: col=l15, row=lq*4+r) ----
    float c2a[4];
#pragma unroll
    for (int n = 0; n < 4; ++n) c2a[n] = wsC2[cg*64 + n*16 + l15];

#pragma unroll
    for (int m = 0; m < 2; ++m)
#pragma unroll
        for (int n = 0; n < 4; ++n)
#pragma unroll
            for (int r = 0; r < 4; ++r) {
                const int rw = rg*32 + m*16 + lq*4 + r;
                float d2 = fmaxf(s_x2[rw] + c2a[n] - 2.0f * acc[m][n][r], 0.0f);
                acc[m][n][r] = 1.0f / (1.0f + d2);
            }

    // ---- row sums: 16-lane shuffle, per-cg slot (deterministic) ----
#pragma unroll
    for (int m = 0; m < 2; ++m)
#pragma unroll
        for (int r = 0; r < 4; ++r) {
            float p = acc[m][0][r] + acc[m][1][r] + acc[m][2][r] + acc[m][3][r];
            p += __shfl_xor(p, 1); p += __shfl_xor(p, 2);
            p += __shfl_xor(p, 4); p += __shfl_xor(p, 8);
            if (l15 == 0) s_rs[cg][rg*32 + m*16 + lq*4 + r] = p;
        }
    __syncthreads();

    // ---- normalize + store ----
#pragma unroll
    for (int m = 0; m < 2; ++m)
#pragma unroll
        for (int r = 0; r < 4; ++r) {
            const int rw = rg*32 + m*16 + lq*4 + r;
            const float rinv = 1.0f / (s_rs[0][rw] + s_rs[1][rw] + s_rs[2][rw] + s_rs[3][rw]);
            float* o = out + (size_t)(row0 + rw) * KCL + cg*64 + l15;
#pragma unroll
            for (int n = 0; n < 4; ++n)
                o[n * 16] = acc[m][n][r] * rinv;
        }
}

extern "C" void kernel_launch(void* const* d_in, const int* in_sizes, int n_in,
                              void* d_out, int out_size, void* d_ws, size_t ws_size,
                              hipStream_t stream) {
    const float* x  = (const float*)d_in[0];
    const float* cl = (const float*)d_in[1];
    float* out = (float*)d_out;
    short* wsB  = (short*)d_ws;
    float* wsC2 = (float*)((char*)d_ws + (size_t)NTILES * BTILE * sizeof(short)); // +256 KB

    prep<<<80, 256, 0, stream>>>(cl, wsB, wsC2);
    const int B = in_sizes[0] / DDIM;     // 65536
    dec_main<<<B / BM, NT, 0, stream>>>(x, wsB, wsC2, out);
}